// Round 9
// baseline (106.566 us; speedup 1.0000x reference)
//
#include <hip/hip_runtime.h>

typedef float f4 __attribute__((ext_vector_type(4)));
typedef float f2 __attribute__((ext_vector_type(2)));

#define NJ 24
#define BLK 256               // 4 waves/block
#define OUTW 75               // (NJ+1)*3 floats per row
#define RPW 16                // rows per wave (4 lanes cooperate per row)
#define RPB 64                // rows per block
#define CW 12                 // per-joint consts: qA[4], qB[4], xyz[3], halfnorm

__global__ __launch_bounds__(BLK, 5) void fk_main_kernel(
    const float* __restrict__ ang,   // (B, 24)
    const float* __restrict__ xyz,   // (24, 3)
    const float* __restrict__ rpy,   // (24, 3)
    const float* __restrict__ axis,  // (24, 3)
    float* __restrict__ out)         // (B, 75)
{
    __shared__ float lcst[NJ * CW];      // 1152 B
    __shared__ float buf[RPB * OUTW];    // 19200 B, per-wave 16-row slices

    const int tid = threadIdx.x;
    const int wv = tid >> 6, ln = tid & 63;
    const int q = ln & 3, r = ln >> 2;   // quad-slot, row-within-wave

    const long long row = (long long)blockIdx.x * RPB + wv * RPW + r;

    // ---- my segment's 6 angles (joints 6q..6q+5): 3x aligned f2 loads ----
    const f2* ga = (const f2*)(ang + row * NJ + q * 6);
    f2 a0 = ga[0], a1 = ga[1], a2 = ga[2];
    float th[6] = {a0.x, a0.y, a1.x, a1.y, a2.x, a2.y};

    // ---- per-joint constants (block threads 0..23): quaternionized ----
    if (tid < NJ) {
        const int j = tid;
        float rr = rpy[j*3+0] * 0.5f, p = rpy[j*3+1] * 0.5f, yv = rpy[j*3+2] * 0.5f;
        float sr, cr, sp, cp, sy, cy;
        __sincosf(rr, &sr, &cr);
        __sincosf(p,  &sp, &cp);
        __sincosf(yv, &sy, &cy);
        float qw = cr*cp*cy + sr*sp*sy;
        float qx = sr*cp*cy - cr*sp*sy;
        float qy = cr*sp*cy + sr*cp*sy;
        float qz = cr*cp*sy - sr*sp*cy;
        float ax = axis[j*3+0], ay = axis[j*3+1], az = axis[j*3+2];
        float n = sqrtf(ax*ax + ay*ay + az*az);
        float inv = 1.0f / fmaxf(n, 1e-6f);
        float ux = ax*inv, uy = ay*inv, uz = az*inv;
        float* c = &lcst[j * CW];
        c[0] = qw; c[1] = qx; c[2] = qy; c[3] = qz;        // qA = qRo
        c[4] = -(qx*ux + qy*uy + qz*uz);                    // qB = qRo x (0,u)
        c[5] = qw*ux + qy*uz - qz*uy;
        c[6] = qw*uy + qz*ux - qx*uz;
        c[7] = qw*uz + qx*uy - qy*ux;
        c[8] = xyz[j*3+0]; c[9] = xyz[j*3+1]; c[10] = xyz[j*3+2];
        c[11] = n * 0.5f;
    }
    __syncthreads();

    // ---- segment-local chain from identity: 6 joints, record local positions
    float Qw=1.f,Qx=0.f,Qy=0.f,Qz=0.f, t0=0.f,t1=0.f,t2=0.f;
    float plx[6], ply[6], plz[6];
    #pragma unroll
    for (int i = 0; i < 6; ++i) {
        const float* cc = &lcst[(q*6 + i) * CW];  // 4 distinct addrs, 288B apart
        float h = th[i] * cc[11];
        float s, cq;
        __sincosf(h, &s, &cq);
        float lw = cq*cc[0] + s*cc[4];
        float lx = cq*cc[1] + s*cc[5];
        float ly = cq*cc[2] + s*cc[6];
        float lz = cq*cc[3] + s*cc[7];
        float vx = cc[8], vy = cc[9], vz = cc[10];
        float px = Qy*vz - Qz*vy + Qw*vx;
        float py = Qz*vx - Qx*vz + Qw*vy;
        float pz = Qx*vy - Qy*vx + Qw*vz;
        t0 += vx + 2.f*(Qy*pz - Qz*py);
        t1 += vy + 2.f*(Qz*px - Qx*pz);
        t2 += vz + 2.f*(Qx*py - Qy*px);
        plx[i] = t0; ply[i] = t1; plz[i] = t2;
        float nw = Qw*lw - Qx*lx - Qy*ly - Qz*lz;
        float nx = Qw*lx + Qx*lw + Qy*lz - Qz*ly;
        float ny = Qw*ly - Qx*lz + Qy*lw + Qz*lx;
        float nz = Qw*lz + Qx*ly - Qy*lx + Qz*lw;
        Qw = nw; Qx = nx; Qy = ny; Qz = nz;
    }

    // ---- inclusive Kogge-Stone prefix-compose over the quad (width 4) ----
    // transform = (Q, t); compose (Ja,Jt) o (Ia,It) = (Ja@Ia, Jt + rot(Ja,It))
    float Iw=Qw, Ix=Qx, Iy=Qy, Iz=Qz, It0=t0, It1=t1, It2=t2;
    #pragma unroll
    for (int d = 1; d < 4; d <<= 1) {
        float Jw  = __shfl_up(Iw, d, 4);
        float Jx  = __shfl_up(Ix, d, 4);
        float Jy  = __shfl_up(Iy, d, 4);
        float Jz  = __shfl_up(Iz, d, 4);
        float Jt0 = __shfl_up(It0, d, 4);
        float Jt1 = __shfl_up(It1, d, 4);
        float Jt2 = __shfl_up(It2, d, 4);
        if (q >= d) {
            float px = Jy*It2 - Jz*It1 + Jw*It0;
            float py = Jz*It0 - Jx*It2 + Jw*It1;
            float pz = Jx*It1 - Jy*It0 + Jw*It2;
            float r0 = It0 + 2.f*(Jy*pz - Jz*py);
            float r1 = It1 + 2.f*(Jz*px - Jx*pz);
            float r2 = It2 + 2.f*(Jx*py - Jy*px);
            It0 = Jt0 + r0; It1 = Jt1 + r1; It2 = Jt2 + r2;
            float nw = Jw*Iw - Jx*Ix - Jy*Iy - Jz*Iz;
            float nx = Jw*Ix + Jx*Iw + Jy*Iz - Jz*Iy;
            float ny = Jw*Iy - Jx*Iz + Jy*Iw + Jz*Ix;
            float nz = Jw*Iz + Jx*Iy - Jy*Ix + Jz*Iw;
            Iw = nw; Ix = nx; Iy = ny; Iz = nz;
        }
    }
    // exclusive prefix P_q = I_{q-1}; identity for q==0
    float Pw  = __shfl_up(Iw, 1, 4);
    float Px  = __shfl_up(Ix, 1, 4);
    float Py  = __shfl_up(Iy, 1, 4);
    float Pz  = __shfl_up(Iz, 1, 4);
    float Pt0 = __shfl_up(It0, 1, 4);
    float Pt1 = __shfl_up(It1, 1, 4);
    float Pt2 = __shfl_up(It2, 1, 4);
    if (q == 0) { Pw = 1.f; Px = 0.f; Py = 0.f; Pz = 0.f;
                  Pt0 = 0.f; Pt1 = 0.f; Pt2 = 0.f; }

    // ---- rotate local positions into global frame, stage into row slice ----
    float* ob = &buf[(wv * RPW + r) * OUTW];
    if (q == 0) { ob[0] = 0.f; ob[1] = 0.f; ob[2] = 0.f; }
    #pragma unroll
    for (int i = 0; i < 6; ++i) {
        float vx = plx[i], vy = ply[i], vz = plz[i];
        float px = Py*vz - Pz*vy + Pw*vx;
        float py = Pz*vx - Px*vz + Pw*vy;
        float pz = Px*vy - Py*vx + Pw*vz;
        int c = (q*6 + i + 1) * 3;
        ob[c+0] = Pt0 + vx + 2.f*(Py*pz - Pz*py);
        ob[c+1] = Pt1 + vy + 2.f*(Pz*px - Px*pz);
        ob[c+2] = Pt2 + vz + 2.f*(Px*py - Py*px);
    }

    asm volatile("" ::: "memory");   // stage-writes -> dump-reads program order
    // (DS pipe is in-order per wave; waves touch disjoint 16-row slices, so
    //  no block barrier is needed after the initial lcst sync.)

    // ---- per-wave coalesced dump: 16 rows x 75 = 300 f4, contiguous 4.8KB ----
    const f4* lb = (const f4*)&buf[wv * RPW * OUTW];
    f4* gO = (f4*)(out + (long long)blockIdx.x * (RPB * OUTW) + wv * (RPW * OUTW));
    #pragma unroll
    for (int k = 0; k < 5; ++k) {
        int i = k * 64 + ln;
        if (i < (RPW * OUTW) / 4) gO[i] = lb[i];
    }
}

extern "C" void kernel_launch(void* const* d_in, const int* in_sizes, int n_in,
                              void* d_out, int out_size, void* d_ws, size_t ws_size,
                              hipStream_t stream) {
    const float* ang  = (const float*)d_in[0];
    const float* xyz  = (const float*)d_in[1];
    const float* rpy  = (const float*)d_in[2];
    const float* axis = (const float*)d_in[3];
    float* out = (float*)d_out;

    const int B = in_sizes[0] / NJ;          // 262144
    const int grid = B / RPB;                // 4096 blocks of 256 threads
    fk_main_kernel<<<grid, BLK, 0, stream>>>(ang, xyz, rpy, axis, out);
}

// Round 10
// 27.700 us; speedup vs baseline: 3.8471x; 3.8471x over previous
//
#include <hip/hip_runtime.h>

typedef float f4 __attribute__((ext_vector_type(4)));

#define NJ 24
#define BLK 128
#define OUTW 75               // (NJ+1)*3 floats per row
#define HROWS 32              // rows staged per dump phase (half wave)
#define HBUF (HROWS * OUTW)   // 2400 floats = 9.6 KB per wave
#define CW 12                 // per-joint consts: qA[4], qB[4], xyz[3], halfnorm

__global__ __launch_bounds__(BLK, 4) void fk_main_kernel(
    const float* __restrict__ ang,   // (B, 24)
    const float* __restrict__ xyz,   // (24, 3)
    const float* __restrict__ rpy,   // (24, 3)
    const float* __restrict__ axis,  // (24, 3)
    float* __restrict__ out)         // (B, 75)
{
    __shared__ float lcst[NJ * CW];            // 1152 B
    __shared__ float buf[(BLK / 64) * HBUF];   // 2 x 9.6 KB per-wave regions

    const int tid = threadIdx.x;
    const int wv = tid >> 6, ln = tid & 63;
    float* wbuf = &buf[wv * HBUF];

    // ---- my row's 24 angles via 6x float4 (row base 96B -> 16B aligned) ----
    const long long row = (long long)blockIdx.x * BLK + tid;
    const f4* gA = (const f4*)(ang + row * NJ);
    f4 A[6];
    #pragma unroll
    for (int k = 0; k < 6; ++k) A[k] = gA[k];

    // ---- per-joint constants (tid 0..23): quaternionized ----
    if (tid < NJ) {
        const int j = tid;
        float r = rpy[j*3+0] * 0.5f, p = rpy[j*3+1] * 0.5f, yv = rpy[j*3+2] * 0.5f;
        float sr, cr, sp, cp, sy, cy;
        __sincosf(r, &sr, &cr);
        __sincosf(p, &sp, &cp);
        __sincosf(yv, &sy, &cy);
        float qw = cr*cp*cy + sr*sp*sy;
        float qx = sr*cp*cy - cr*sp*sy;
        float qy = cr*sp*cy + sr*cp*sy;
        float qz = cr*cp*sy - sr*sp*cy;
        float ax = axis[j*3+0], ay = axis[j*3+1], az = axis[j*3+2];
        float n = sqrtf(ax*ax + ay*ay + az*az);
        float inv = 1.0f / fmaxf(n, 1e-6f);
        float ux = ax*inv, uy = ay*inv, uz = az*inv;
        float* c = &lcst[j * CW];
        c[0] = qw; c[1] = qx; c[2] = qy; c[3] = qz;        // qA = qRo
        c[4] = -(qx*ux + qy*uy + qz*uz);                    // qB = qRo x (0,u)
        c[5] = qw*ux + qy*uz - qz*uy;
        c[6] = qw*uy + qz*ux - qx*uz;
        c[7] = qw*uz + qx*uy - qy*ux;
        c[8] = xyz[j*3+0]; c[9] = xyz[j*3+1]; c[10] = xyz[j*3+2];
        c[11] = n * 0.5f;
    }
    __syncthreads();   // the only block-wide sync in the kernel

    // ---- single FK chain per thread; positions accumulate in REGISTERS ----
    float o[OUTW];                       // all indices compile-time -> VGPRs
    o[0] = 0.f; o[1] = 0.f; o[2] = 0.f;
    float Qw = 1.f, Qx = 0.f, Qy = 0.f, Qz = 0.f;
    float t0 = 0.f, t1 = 0.f, t2 = 0.f;

    #pragma unroll
    for (int j = 0; j < NJ; ++j) {
        const float* cc = &lcst[j * CW];   // wave-uniform -> LDS broadcast
        float h = A[j >> 2][j & 3] * cc[11];
        float s, cq;
        __sincosf(h, &s, &cq);
        float lw = cq*cc[0] + s*cc[4];
        float lx = cq*cc[1] + s*cc[5];
        float ly = cq*cc[2] + s*cc[6];
        float lz = cq*cc[3] + s*cc[7];
        float vx = cc[8], vy = cc[9], vz = cc[10];
        float px = Qy*vz - Qz*vy + Qw*vx;
        float py = Qz*vx - Qx*vz + Qw*vy;
        float pz = Qx*vy - Qy*vx + Qw*vz;
        t0 += vx + 2.f*(Qy*pz - Qz*py);
        t1 += vy + 2.f*(Qz*px - Qx*pz);
        t2 += vz + 2.f*(Qx*py - Qy*px);
        float nw = Qw*lw - Qx*lx - Qy*ly - Qz*lz;
        float nx = Qw*lx + Qx*lw + Qy*lz - Qz*ly;
        float ny = Qw*ly - Qx*lz + Qy*lw + Qz*lx;
        float nz = Qw*lz + Qx*ly - Qy*lx + Qz*lw;
        Qw = nw; Qx = nx; Qy = ny; Qz = nz;
        o[3*(j+1)+0] = t0;
        o[3*(j+1)+1] = t1;
        o[3*(j+1)+2] = t2;
    }

    // global f4 base for this wave's 64 rows (64*75*4 = 19200 B contiguous)
    f4* gW = (f4*)(out + ((long long)blockIdx.x * BLK + wv * 64) * OUTW);

    // ---- phase 0: lanes 0..31 stage their full rows; whole wave dumps ----
    // staging: addr = ln*75 + k floats -> bank (11*ln + k) mod 32, bijective
    // in ln -> conflict-free. LDS ptrs deliberately NOT restrict (alias!).
    if (ln < HROWS) {
        float* ob = wbuf + ln * OUTW;
        #pragma unroll
        for (int k = 0; k < OUTW; ++k) ob[k] = o[k];
    }
    asm volatile("" ::: "memory");   // stage-writes -> dump-reads (RAW order)
    {
        const f4* lb = (const f4*)wbuf;          // 600 f4, contiguous
        #pragma unroll
        for (int k = 0; k < 10; ++k) {
            int i = k * 64 + ln;
            if (i < HBUF / 4) gW[i] = lb[i];
        }
    }
    asm volatile("" ::: "memory");   // dump-reads -> phase-1 stage-writes (WAR)

    // ---- phase 1: lanes 32..63 stage; whole wave dumps second half ----
    if (ln >= HROWS) {
        float* ob = wbuf + (ln - HROWS) * OUTW;
        #pragma unroll
        for (int k = 0; k < OUTW; ++k) ob[k] = o[k];
    }
    asm volatile("" ::: "memory");   // stage-writes -> dump-reads (RAW order)
    {
        const f4* lb = (const f4*)wbuf;
        #pragma unroll
        for (int k = 0; k < 10; ++k) {
            int i = k * 64 + ln;
            if (i < HBUF / 4) gW[i + HBUF / 4] = lb[i];
        }
    }
}

extern "C" void kernel_launch(void* const* d_in, const int* in_sizes, int n_in,
                              void* d_out, int out_size, void* d_ws, size_t ws_size,
                              hipStream_t stream) {
    const float* ang  = (const float*)d_in[0];
    const float* xyz  = (const float*)d_in[1];
    const float* rpy  = (const float*)d_in[2];
    const float* axis = (const float*)d_in[3];
    float* out = (float*)d_out;

    const int B = in_sizes[0] / NJ;          // 262144
    const int grid = B / BLK;                // 2048 = 8 blocks/CU, one round
    fk_main_kernel<<<grid, BLK, 0, stream>>>(ang, xyz, rpy, axis, out);
}